// Round 1
// baseline (3468.430 us; speedup 1.0000x reference)
//
#include <hip/hip_runtime.h>

// RSNN forward: B=128, T=512, IN=128, N=512, OUT=128, fp32 in/out.
// d_out = [vt (128*513*512) | zt (128*513*512) | out (128*512*128)] fp32.
// zt-region slot (b, t+1, :) lifecycle: Xp (phase1) -> lamb (phase2) -> z (phase5).

typedef __attribute__((ext_vector_type(8))) short short8x;
typedef __attribute__((ext_vector_type(4))) float f32x4;

// ---- workspace layout (bytes) ----
#define OFF_JPK  (0u)        // J packed bf16:   16*4*512*8*2 = 524288
#define OFF_BWH  (524288u)   // Bw hi bf16:       4*4*512*8*2 = 131072
#define OFF_BWL  (655360u)   // Bw lo
#define OFF_WH   (786432u)   // W hi bf16:       16*4*128*8*2 = 131072
#define OFF_WL   (917504u)   // W lo
#define OFF_SXP  (1048576u)  // s exchange: 8 groups * 2 bufs * 16*512 bf16 = 262144
#define OFF_CNT  (1310720u)  // barrier counters: 8 groups * 64B

__device__ __forceinline__ unsigned short f2bf(float f) {
  union { float f; unsigned u; } a; a.f = f;
  unsigned r = a.u + 0x7FFFu + ((a.u >> 16) & 1u);   // RNE bf16
  return (unsigned short)(r >> 16);
}
__device__ __forceinline__ float bf2f(unsigned short h) {
  union { unsigned u; float f; } a; a.u = ((unsigned)h) << 16;
  return a.f;
}
// Must be bit-identical between recur_kernel and zfin_kernel.
__device__ __forceinline__ float spike_prob(float lam) {
  const float vv = (lam - 0.4f) / 0.4f;
  return 1.0f / (1.0f + __expf(-0.1f * vv));
}
__device__ __forceinline__ float fast_tanh_pos(float x) {  // x >= 0 always here
  const float e2 = __expf(2.0f * x);
  return 1.0f - 2.0f / (e2 + 1.0f);
}

// ---------------- phase -1: init (barrier counters + t=0 slots) ----------------
__global__ void init_kernel(unsigned char* __restrict__ ws, float* __restrict__ vt,
                            float* __restrict__ zt) {
  const int idx = blockIdx.x * 256 + threadIdx.x;  // grid 256 -> 65536 threads
  if (idx < 65536) {
    const int b = idx >> 9, n = idx & 511;
    const size_t a = (size_t)b * 513 * 512 + n;    // slot (b, 0, n)
    vt[a] = 0.0f;
    zt[a] = 0.0f;
  }
  if (idx < 128) ((unsigned int*)(ws + OFF_CNT))[idx] = 0u;
}

// ---------------- phase 0: pack weights into MFMA B-fragment layouts ----------------
// Jpk[(kt*4+g)*512 + n][e]  = bf16( J[n][ (kt*4+g)*8 + e ] ),   kt<16
// Bw{h,l}[(kt*4+g)*512+n][e]= split( Bw[n][ (kt*4+g)*8 + e ] ), kt<4
// W{h,l}[(kt*4+g)*128+o][e] = split( W[o][ (kt*4+g)*8 + e ] ),  kt<16
__global__ void pack_kernel(const float* __restrict__ J, const float* __restrict__ Bw,
                            const float* __restrict__ W, unsigned char* __restrict__ ws) {
  const int id = blockIdx.x * 256 + threadIdx.x;   // grid 192 -> 49152
  unsigned short* jpk = (unsigned short*)(ws + OFF_JPK);
  unsigned short* bwh = (unsigned short*)(ws + OFF_BWH);
  unsigned short* bwl = (unsigned short*)(ws + OFF_BWL);
  unsigned short* wh  = (unsigned short*)(ws + OFF_WH);
  unsigned short* wl  = (unsigned short*)(ws + OFF_WL);
  if (id < 32768) {
    const int idx = id;               // (kt*4+g)*512 + n
    const int n = idx & 511, kg = idx >> 9, k0 = kg * 8;
    for (int e = 0; e < 8; ++e) jpk[(size_t)idx * 8 + e] = f2bf(J[(size_t)n * 512 + k0 + e]);
  } else if (id < 40960) {
    const int idx = id - 32768;       // (kt*4+g)*512 + n, kt<4
    const int n = idx & 511, kg = idx >> 9, k0 = kg * 8;
    for (int e = 0; e < 8; ++e) {
      const float x = Bw[(size_t)n * 128 + k0 + e];
      const unsigned short h = f2bf(x);
      bwh[(size_t)idx * 8 + e] = h;
      bwl[(size_t)idx * 8 + e] = f2bf(x - bf2f(h));
    }
  } else if (id < 49152) {
    const int idx = id - 40960;       // (kt*4+g)*128 + o, kt<16
    const int o = idx & 127, kg = idx >> 7, k0 = kg * 8;
    for (int e = 0; e < 8; ++e) {
      const float x = W[(size_t)o * 512 + k0 + e];
      const unsigned short h = f2bf(x);
      wh[(size_t)idx * 8 + e] = h;
      wl[(size_t)idx * 8 + e] = f2bf(x - bf2f(h));
    }
  }
}

// ---------------- phase 1: Xp = inputs @ Bw^T  (split bf16, 3 MFMA) ----------------
// writes Xp[b][t][n] into zt-region slot (b, t+1, n)
__launch_bounds__(256)
__global__ void xp_kernel(const float* __restrict__ X, const unsigned char* __restrict__ ws,
                          float* __restrict__ zt) {
  __shared__ short Ah[64 * 136];  // 64 rows x 128 k, pad 8 -> stride 136 shorts (272 B)
  __shared__ short Al[64 * 136];
  const unsigned short* bwh = (const unsigned short*)(ws + OFF_BWH);
  const unsigned short* bwl = (const unsigned short*)(ws + OFF_BWL);
  const int m0 = blockIdx.x * 64;   // bt rows
  const int n0 = blockIdx.y * 64;   // neuron cols
  const int tid = threadIdx.x;
  for (int i = tid; i < 64 * 32; i += 256) {       // stage + split X tile
    const int r = i >> 5, kq = i & 31;
    const float4 x4 = *(const float4*)(X + (size_t)(m0 + r) * 128 + kq * 4);
    short4 h4, l4; unsigned short h;
    h = f2bf(x4.x); h4.x = (short)h; l4.x = (short)f2bf(x4.x - bf2f(h));
    h = f2bf(x4.y); h4.y = (short)h; l4.y = (short)f2bf(x4.y - bf2f(h));
    h = f2bf(x4.z); h4.z = (short)h; l4.z = (short)f2bf(x4.z - bf2f(h));
    h = f2bf(x4.w); h4.w = (short)h; l4.w = (short)f2bf(x4.w - bf2f(h));
    *(short4*)(&Ah[r * 136 + kq * 4]) = h4;
    *(short4*)(&Al[r * 136 + kq * 4]) = l4;
  }
  __syncthreads();
  const int w = tid >> 6, l = tid & 63, lhi = l >> 4, llo = l & 15;
  const int rowA = 16 * w + llo;
  f32x4 a0 = {0,0,0,0}, a1 = {0,0,0,0}, a2 = {0,0,0,0}, a3 = {0,0,0,0};
#pragma unroll
  for (int kt = 0; kt < 4; ++kt) {
    const short8x ah = *(const short8x*)(&Ah[rowA * 136 + kt * 32 + lhi * 8]);
    const short8x al = *(const short8x*)(&Al[rowA * 136 + kt * 32 + lhi * 8]);
#define XT(TI, ACC) { \
    const size_t bi = ((size_t)((kt * 4 + lhi) * 512 + n0 + TI * 16 + llo)) * 8; \
    const short8x bh = *(const short8x*)(bwh + bi); \
    const short8x bl = *(const short8x*)(bwl + bi); \
    ACC = __builtin_amdgcn_mfma_f32_16x16x32_bf16(ah, bh, ACC, 0, 0, 0); \
    ACC = __builtin_amdgcn_mfma_f32_16x16x32_bf16(al, bh, ACC, 0, 0, 0); \
    ACC = __builtin_amdgcn_mfma_f32_16x16x32_bf16(ah, bl, ACC, 0, 0, 0); }
    XT(0, a0) XT(1, a1) XT(2, a2) XT(3, a3)
#undef XT
  }
#pragma unroll
  for (int r = 0; r < 4; ++r) {
    const int bt = m0 + 16 * w + lhi * 4 + r;
    const int b = bt >> 9, t = bt & 511;
    float* s = zt + ((size_t)b * 513 + t + 1) * 512 + n0 + llo;
    s[0] = a0[r]; s[16] = a1[r]; s[32] = a2[r]; s[48] = a3[r];
  }
}

// ---------------- phase 2: sequential recurrence ----------------
// 32 WGs = 8 groups (16 b each) x 4 slices (128 n each). J-slice lives in VGPRs.
// Per step: v,s update -> device-scope s exchange -> monotonic-counter barrier
// (4 arrivals, double-buffered s => 1 barrier/step) -> 32 MFMA -> spike epilogue.
__launch_bounds__(256, 1)
__global__ void recur_kernel(const float* __restrict__ U, unsigned char* __restrict__ ws,
                             float* __restrict__ vt, float* __restrict__ zt) {
  const int wg = blockIdx.x;       // 0..31
  const int g = wg >> 2;           // group
  const int p = wg & 3;            // n-slice
  const int tid = threadIdx.x;
  const int w = tid >> 6, l = tid & 63;
  const int lhi = l >> 4, llo = l & 15;
  const int b0 = g * 16;
  const unsigned short* __restrict__ jpk = (const unsigned short*)(ws + OFF_JPK);
  unsigned int* sx = (unsigned int*)(ws + OFF_SXP) + (size_t)g * 8192;  // 2 bufs x 4096 dwords
  unsigned int* cn = (unsigned int*)(ws + OFF_CNT) + g * 16;

  const int ntA = p * 8 + 2 * w;          // this wave's two n-tiles
  const int nA = ntA * 16 + llo;
  const int nB = nA + 16;

  short8x jf0[16], jf1[16];               // J B-fragments, register-resident (static idx)
#pragma unroll
  for (int kt = 0; kt < 16; ++kt) {
    jf0[kt] = *(const short8x*)(jpk + ((size_t)((kt * 4 + lhi) * 512 + nA)) * 8);
    jf1[kt] = *(const short8x*)(jpk + ((size_t)((kt * 4 + lhi) * 512 + nB)) * 8);
  }

  float v[8], z[8];                       // [j*4+r]: b = b0 + lhi*4 + r, n = {nA,nB}
#pragma unroll
  for (int i = 0; i < 8; ++i) { v[i] = 0.0f; z[i] = 0.0f; }
  const int brow = lhi * 4;

  for (int t = 0; t < 512; ++t) {
    const unsigned bufo = (t & 1) ? 4096u : 0u;
    float sv[8];
#pragma unroll
    for (int i = 0; i < 8; ++i) {
      v[i] = 0.9f * v[i] + 0.1f * z[i];
      sv[i] = fast_tanh_pos(v[i]);
    }
#pragma unroll
    for (int j = 0; j < 2; ++j) {
      const int n = j ? nB : nA;
#pragma unroll
      for (int r = 0; r < 4; ++r) {
        const int b = b0 + brow + r;
        vt[((size_t)b * 513 + (t + 1)) * 512 + n] = v[j * 4 + r];
      }
    }
    // s exchange: even lanes pack (n, n+1) bf16 pair, device-scope store
#pragma unroll
    for (int j = 0; j < 2; ++j) {
      const int n = j ? nB : nA;
#pragma unroll
      for (int r = 0; r < 4; ++r) {
        const float mine = sv[j * 4 + r];
        const float other = __shfl_xor(mine, 1);
        if ((l & 1) == 0) {
          const unsigned pk = (unsigned)f2bf(mine) | ((unsigned)f2bf(other) << 16);
          __hip_atomic_store(&sx[bufo + (unsigned)(brow + r) * 256 + (unsigned)(n >> 1)], pk,
                             __ATOMIC_RELAXED, __HIP_MEMORY_SCOPE_AGENT);
        }
      }
    }
    __syncthreads();   // drains vmcnt -> stores performed before arrival
    if (tid == 0) {
      __hip_atomic_fetch_add(cn, 1u, __ATOMIC_RELAXED, __HIP_MEMORY_SCOPE_AGENT);
      const unsigned target = 4u * (unsigned)(t + 1);
      long guard = 0;
      while (__hip_atomic_load(cn, __ATOMIC_RELAXED, __HIP_MEMORY_SCOPE_AGENT) < target) {
        __builtin_amdgcn_s_sleep(2);
        if (++guard > 100000000L) break;   // converts a protocol bug into wrong-answer, not hang
      }
    }
    __syncthreads();
    // MFMA: lamb[16 b x 32 n] over K=512
    f32x4 acc0 = {0,0,0,0}, acc1 = {0,0,0,0};
#pragma unroll
    for (int kt = 0; kt < 16; ++kt) {
      const unsigned idx = bufo + (unsigned)llo * 256 + (unsigned)(kt * 16 + lhi * 4);
      unsigned long long q0 = __hip_atomic_load((unsigned long long*)&sx[idx],
                                                __ATOMIC_RELAXED, __HIP_MEMORY_SCOPE_AGENT);
      unsigned long long q1 = __hip_atomic_load((unsigned long long*)&sx[idx + 2],
                                                __ATOMIC_RELAXED, __HIP_MEMORY_SCOPE_AGENT);
      union { unsigned long long q[2]; short8x s; } au;
      au.q[0] = q0; au.q[1] = q1;
      acc0 = __builtin_amdgcn_mfma_f32_16x16x32_bf16(au.s, jf0[kt], acc0, 0, 0, 0);
      acc1 = __builtin_amdgcn_mfma_f32_16x16x32_bf16(au.s, jf1[kt], acc1, 0, 0, 0);
    }
    // epilogue: lamb = acc + Xp (slot), store lamb to slot, spike
#pragma unroll
    for (int j = 0; j < 2; ++j) {
      const int n = j ? nB : nA;
      const f32x4 ac = j ? acc1 : acc0;
#pragma unroll
      for (int r = 0; r < 4; ++r) {
        const int b = b0 + brow + r;
        const size_t slot = ((size_t)b * 513 + (t + 1)) * 512 + n;
        const float lam = ac[r] + zt[slot];
        zt[slot] = lam;
        const float uu = U[((size_t)b * 512 + t) * 512 + n];
        z[j * 4 + r] = (spike_prob(lam) > uu) ? 1.0f : 0.0f;
      }
    }
  }
}

// ---------------- phase 3: out = lamb @ W^T  (split bf16) ----------------
__launch_bounds__(256)
__global__ void out_kernel(const unsigned char* __restrict__ ws,
                           const float* __restrict__ zt, float* __restrict__ outp) {
  __shared__ short Lh[64 * 520];  // 64 rows x 512 k, pad 8 (133 KB total LDS)
  __shared__ short Ll[64 * 520];
  const unsigned short* wh = (const unsigned short*)(ws + OFF_WH);
  const unsigned short* wl = (const unsigned short*)(ws + OFF_WL);
  const int m0 = blockIdx.x * 64;
  const int tid = threadIdx.x;
  for (int i = tid; i < 64 * 128; i += 256) {
    const int r = i >> 7, kq = i & 127;
    const int bt = m0 + r, b = bt >> 9, t = bt & 511;
    const float4 x4 = *(const float4*)(zt + ((size_t)b * 513 + t + 1) * 512 + kq * 4);
    short4 h4, l4; unsigned short h;
    h = f2bf(x4.x); h4.x = (short)h; l4.x = (short)f2bf(x4.x - bf2f(h));
    h = f2bf(x4.y); h4.y = (short)h; l4.y = (short)f2bf(x4.y - bf2f(h));
    h = f2bf(x4.z); h4.z = (short)h; l4.z = (short)f2bf(x4.z - bf2f(h));
    h = f2bf(x4.w); h4.w = (short)h; l4.w = (short)f2bf(x4.w - bf2f(h));
    *(short4*)(&Lh[r * 520 + kq * 4]) = h4;
    *(short4*)(&Ll[r * 520 + kq * 4]) = l4;
  }
  __syncthreads();
  const int w = tid >> 6, l = tid & 63, lhi = l >> 4, llo = l & 15;
  const int rowA = 16 * w + llo;
  f32x4 a0={0,0,0,0},a1={0,0,0,0},a2={0,0,0,0},a3={0,0,0,0},
        a4={0,0,0,0},a5={0,0,0,0},a6={0,0,0,0},a7={0,0,0,0};
#pragma unroll
  for (int kt = 0; kt < 16; ++kt) {
    const short8x ah = *(const short8x*)(&Lh[rowA * 520 + kt * 32 + lhi * 8]);
    const short8x al = *(const short8x*)(&Ll[rowA * 520 + kt * 32 + lhi * 8]);
#define OT(TI, ACC) { \
    const size_t bi = ((size_t)((kt * 4 + lhi) * 128 + TI * 16 + llo)) * 8; \
    const short8x bh = *(const short8x*)(wh + bi); \
    const short8x bl = *(const short8x*)(wl + bi); \
    ACC = __builtin_amdgcn_mfma_f32_16x16x32_bf16(ah, bh, ACC, 0, 0, 0); \
    ACC = __builtin_amdgcn_mfma_f32_16x16x32_bf16(al, bh, ACC, 0, 0, 0); \
    ACC = __builtin_amdgcn_mfma_f32_16x16x32_bf16(ah, bl, ACC, 0, 0, 0); }
    OT(0, a0) OT(1, a1) OT(2, a2) OT(3, a3) OT(4, a4) OT(5, a5) OT(6, a6) OT(7, a7)
#undef OT
  }
#pragma unroll
  for (int r = 0; r < 4; ++r) {
    const int bt = m0 + 16 * w + lhi * 4 + r;
    float* o = outp + (size_t)bt * 128 + llo;
    o[0]  = a0[r]; o[16] = a1[r]; o[32] = a2[r]; o[48] = a3[r];
    o[64] = a4[r]; o[80] = a5[r]; o[96] = a6[r]; o[112] = a7[r];
  }
}

// ---------------- phase 4: finalize zt (z = spike(lamb, u)) ----------------
__global__ void zfin_kernel(const float* __restrict__ U, float* __restrict__ zt) {
  const size_t base = ((size_t)blockIdx.x * 256 + threadIdx.x) * 4;  // grid 32768
  const int b = (int)(base >> 18);
  const int t = (int)((base >> 9) & 511);
  const int n = (int)(base & 511);
  float* zp = zt + ((size_t)b * 513 + t + 1) * 512 + n;
  const float4 lam = *(const float4*)zp;
  const float4 uu = *(const float4*)(U + base);
  float4 zv;
  zv.x = (spike_prob(lam.x) > uu.x) ? 1.0f : 0.0f;
  zv.y = (spike_prob(lam.y) > uu.y) ? 1.0f : 0.0f;
  zv.z = (spike_prob(lam.z) > uu.z) ? 1.0f : 0.0f;
  zv.w = (spike_prob(lam.w) > uu.w) ? 1.0f : 0.0f;
  *(float4*)zp = zv;
}

extern "C" void kernel_launch(void* const* d_in, const int* in_sizes, int n_in,
                              void* d_out, int out_size, void* d_ws, size_t ws_size,
                              hipStream_t stream) {
  const float* X  = (const float*)d_in[0];   // inputs [128,512,128]
  const float* U  = (const float*)d_in[1];   // rand_u [128,512,512]
  const float* J  = (const float*)d_in[2];   // [512,512]
  const float* Bw = (const float*)d_in[3];   // [512,128]
  const float* W  = (const float*)d_in[4];   // [128,512]
  float* vt = (float*)d_out;
  float* zt = vt + (size_t)128 * 513 * 512;
  float* op = vt + (size_t)2 * 128 * 513 * 512;
  unsigned char* ws = (unsigned char*)d_ws;
  init_kernel<<<256, 256, 0, stream>>>(ws, vt, zt);
  pack_kernel<<<192, 256, 0, stream>>>(J, Bw, W, ws);
  xp_kernel<<<dim3(1024, 8), 256, 0, stream>>>(X, ws, zt);
  recur_kernel<<<32, 256, 0, stream>>>(U, ws, vt, zt);
  out_kernel<<<1024, 256, 0, stream>>>(ws, zt, op);
  zfin_kernel<<<32768, 256, 0, stream>>>(U, zt);
}

// Round 3
// 1232.934 us; speedup vs baseline: 2.8132x; 2.8132x over previous
//
#include <hip/hip_runtime.h>

// RSNN forward: B=128, T=512, IN=128, N=512, OUT=128, fp32 in/out.
// d_out = [vt (128*513*512) | zt (128*513*512) | out (128*512*128)] fp32.
// Slot lifecycle:
//   vt slot (b,t+1,:): thr(u) (uth_kernel) -> v (recur)
//   zt slot (b,t+1,:): Xp (xp_kernel) -> lamb (recur) -> z (zfin)
// recur: 16 WGs x 512 thr, 8 batches/WG, full J int8-resident in VGPRs,
// s-exchange via LDS only (no cross-WG traffic).

typedef __attribute__((ext_vector_type(8))) short short8x;
typedef __attribute__((ext_vector_type(4))) float f32x4;
typedef __attribute__((ext_vector_type(4))) int i32x4;

// ---- workspace layout (bytes) ----
#define OFF_JQK  (0u)        // J int8 frags: 8kt*4*512 frags * 16B = 262144
#define OFF_BWH  (262144u)   // Bw hi bf16:   4*4*512*8*2 = 131072
#define OFF_BWL  (393216u)   // Bw lo
#define OFF_WH   (524288u)   // W hi bf16:    16*4*128*8*2 = 131072
#define OFF_WL   (655360u)   // W lo

#define SC_J 640.0f
#define SC_S 166.0f

__device__ __forceinline__ unsigned short f2bf(float f) {
  union { float f; unsigned u; } a; a.f = f;
  unsigned r = a.u + 0x7FFFu + ((a.u >> 16) & 1u);   // RNE bf16
  return (unsigned short)(r >> 16);
}
__device__ __forceinline__ float bf2f(unsigned short h) {
  union { unsigned u; float f; } a; a.u = ((unsigned)h) << 16;
  return a.f;
}
// spike(p>u) <=> lamb > thr(u), thr = 0.4 + 4*logit(u).
// MUST be bit-identical between uth_kernel and zfin_kernel.
__device__ __forceinline__ float thr_of(float u) {
  return __builtin_fmaf(4.0f, __logf(u / (1.0f - u)), 0.4f);
}
__device__ __forceinline__ float fast_tanh_pos(float x) {  // x >= 0 here
  const float e2 = __expf(x + x);
  return 1.0f - 2.0f / (e2 + 1.0f);
}

// ---------------- init: zero t=0 slots ----------------
__global__ void init_kernel(float* __restrict__ vt, float* __restrict__ zt) {
  const int idx = blockIdx.x * 256 + threadIdx.x;  // grid 256 -> 65536
  const int b = idx >> 9, n = idx & 511;
  const size_t a = (size_t)b * 513 * 512 + n;      // slot (b, 0, n)
  vt[a] = 0.0f;
  zt[a] = 0.0f;
}

// ---------------- pack: J->int8 frags, Bw/W -> bf16 hi/lo frags ----------------
// JQK frag idx = (kt*4+lhi)*512 + n  (16B = 16 int8, k = idx_hi*16 .. +15)
// Ranges: JQK 16384 | Bw 8192 | W 8192  (total 32768 = 128 blocks x 256)
__global__ void pack_kernel(const float* __restrict__ J, const float* __restrict__ Bw,
                            const float* __restrict__ W, unsigned char* __restrict__ ws) {
  const int id = blockIdx.x * 256 + threadIdx.x;   // grid 128 -> 32768
  if (id < 16384) {
    const int idx = id;                 // (kt*4+lhi)*512 + n
    const int n = idx & 511, kg = idx >> 9, k0 = kg * 16;
    uint4 out;
    unsigned dw[4];
#pragma unroll
    for (int d = 0; d < 4; ++d) {
      unsigned x = 0;
#pragma unroll
      for (int p = 0; p < 4; ++p) {
        const float jv = J[(size_t)n * 512 + k0 + 4 * d + p];
        int q = __float2int_rn(jv * SC_J);
        q = q > 127 ? 127 : (q < -127 ? -127 : q);
        x |= ((unsigned)(q & 255)) << (8 * p);
      }
      dw[d] = x;
    }
    out.x = dw[0]; out.y = dw[1]; out.z = dw[2]; out.w = dw[3];
    ((uint4*)(ws + OFF_JQK))[idx] = out;
  } else if (id < 24576) {
    const int idx = id - 16384;         // (kt*4+g)*512 + n, kt<4  (8192 frags)
    const int n = idx & 511, kg = idx >> 9, k0 = kg * 8;
    unsigned short* bwh = (unsigned short*)(ws + OFF_BWH);
    unsigned short* bwl = (unsigned short*)(ws + OFF_BWL);
    for (int e = 0; e < 8; ++e) {
      const float x = Bw[(size_t)n * 128 + k0 + e];
      const unsigned short h = f2bf(x);
      bwh[(size_t)idx * 8 + e] = h;
      bwl[(size_t)idx * 8 + e] = f2bf(x - bf2f(h));
    }
  } else {
    const int idx = id - 24576;         // (kt*4+g)*128 + o, kt<16  (8192 frags)
    const int o = idx & 127, kg = idx >> 7, k0 = kg * 8;
    unsigned short* wh = (unsigned short*)(ws + OFF_WH);
    unsigned short* wl = (unsigned short*)(ws + OFF_WL);
    for (int e = 0; e < 8; ++e) {
      const float x = W[(size_t)o * 512 + k0 + e];
      const unsigned short h = f2bf(x);
      wh[(size_t)idx * 8 + e] = h;
      wl[(size_t)idx * 8 + e] = f2bf(x - bf2f(h));
    }
  }
}

// ---------------- uth: thr(u) -> vt slots ----------------
__global__ void uth_kernel(const float* __restrict__ U, float* __restrict__ vt) {
  const size_t base = ((size_t)blockIdx.x * 256 + threadIdx.x) * 4;  // grid 32768
  const int b = (int)(base >> 18);
  const int t = (int)((base >> 9) & 511);
  const int n = (int)(base & 511);
  const float4 uu = *(const float4*)(U + base);
  float4 th;
  th.x = thr_of(uu.x); th.y = thr_of(uu.y); th.z = thr_of(uu.z); th.w = thr_of(uu.w);
  *(float4*)(vt + ((size_t)b * 513 + t + 1) * 512 + n) = th;
}

// ---------------- xp: Xp = inputs @ Bw^T (split bf16) -> zt slots ----------------
__launch_bounds__(256)
__global__ void xp_kernel(const float* __restrict__ X, const unsigned char* __restrict__ ws,
                          float* __restrict__ zt) {
  __shared__ short Ah[64 * 136];
  __shared__ short Al[64 * 136];
  const unsigned short* bwh = (const unsigned short*)(ws + OFF_BWH);
  const unsigned short* bwl = (const unsigned short*)(ws + OFF_BWL);
  const int m0 = blockIdx.x * 64;   // bt rows
  const int n0 = blockIdx.y * 64;   // neuron cols
  const int tid = threadIdx.x;
  for (int i = tid; i < 64 * 32; i += 256) {
    const int r = i >> 5, kq = i & 31;
    const float4 x4 = *(const float4*)(X + (size_t)(m0 + r) * 128 + kq * 4);
    short4 h4, l4; unsigned short h;
    h = f2bf(x4.x); h4.x = (short)h; l4.x = (short)f2bf(x4.x - bf2f(h));
    h = f2bf(x4.y); h4.y = (short)h; l4.y = (short)f2bf(x4.y - bf2f(h));
    h = f2bf(x4.z); h4.z = (short)h; l4.z = (short)f2bf(x4.z - bf2f(h));
    h = f2bf(x4.w); h4.w = (short)h; l4.w = (short)f2bf(x4.w - bf2f(h));
    *(short4*)(&Ah[r * 136 + kq * 4]) = h4;
    *(short4*)(&Al[r * 136 + kq * 4]) = l4;
  }
  __syncthreads();
  const int w = tid >> 6, l = tid & 63, lhi = l >> 4, llo = l & 15;
  const int rowA = 16 * w + llo;
  f32x4 a0 = {0,0,0,0}, a1 = {0,0,0,0}, a2 = {0,0,0,0}, a3 = {0,0,0,0};
#pragma unroll
  for (int kt = 0; kt < 4; ++kt) {
    const short8x ah = *(const short8x*)(&Ah[rowA * 136 + kt * 32 + lhi * 8]);
    const short8x al = *(const short8x*)(&Al[rowA * 136 + kt * 32 + lhi * 8]);
#define XT(TI, ACC) { \
    const size_t bi = ((size_t)((kt * 4 + lhi) * 512 + n0 + TI * 16 + llo)) * 8; \
    const short8x bh = *(const short8x*)(bwh + bi); \
    const short8x bl = *(const short8x*)(bwl + bi); \
    ACC = __builtin_amdgcn_mfma_f32_16x16x32_bf16(ah, bh, ACC, 0, 0, 0); \
    ACC = __builtin_amdgcn_mfma_f32_16x16x32_bf16(al, bh, ACC, 0, 0, 0); \
    ACC = __builtin_amdgcn_mfma_f32_16x16x32_bf16(ah, bl, ACC, 0, 0, 0); }
    XT(0, a0) XT(1, a1) XT(2, a2) XT(3, a3)
#undef XT
  }
#pragma unroll
  for (int r = 0; r < 4; ++r) {
    const int bt = m0 + 16 * w + lhi * 4 + r;
    const int b = bt >> 9, t = bt & 511;
    float* s = zt + ((size_t)b * 513 + t + 1) * 512 + n0 + llo;
    s[0] = a0[r]; s[16] = a1[r]; s[32] = a2[r]; s[48] = a3[r];
  }
}

// ---------------- recur: 16 WGs x 512 thr, 8 batches each, no cross-WG traffic ----------------
// Wave w: MFMA n-range [w*64,(w+1)*64) (4 tiles), and tid-linear state for batch b0+w,
// n chunks {l*4..+3, 256+l*4..+3}. J int8 fully VGPR-resident (128 regs/lane).
__launch_bounds__(512)
__global__ void recur_kernel(const unsigned char* __restrict__ ws,
                             float* __restrict__ vt, float* __restrict__ zt) {
  __shared__ unsigned char s_sm[8192];   // s int8 [16 rows alloc][512], rows 0-7 valid
  __shared__ int s_lam[8 * 512];         // raw i32 acc [8][512]
  const int wg = blockIdx.x;             // 0..15
  const int b0 = wg * 8;
  const int tid = threadIdx.x;
  const int w = tid >> 6, l = tid & 63;
  const int lhi = l >> 4, llo = l & 15;

  // J fragments: ji[tile j][kt], 16B each = 128 VGPRs/lane
  const i32x4* jq = (const i32x4*)(ws + OFF_JQK);
  i32x4 ji[4][8];
#pragma unroll
  for (int j = 0; j < 4; ++j)
#pragma unroll
    for (int kt = 0; kt < 8; ++kt)
      ji[j][kt] = jq[(kt * 4 + lhi) * 512 + (w * 4 + j) * 16 + llo];
#pragma unroll
  for (int j = 0; j < 4; ++j)
#pragma unroll
    for (int kt = 0; kt < 8; ++kt)
      asm volatile("" : "+v"(ji[j][kt]));   // pin: forbid rematerialized reloads

  float v[8];
#pragma unroll
  for (int i = 0; i < 8; ++i) v[i] = 0.0f;
  unsigned zb = 0;

  const float SC = 1.0f / (SC_J * SC_S);
  // element offset of slot (b0+w, t+1, l*4); chunk B at +256
  size_t vo = ((size_t)(b0 + w) * 513 + 1) * 512 + l * 4;
  const unsigned sw = (unsigned)((w & 7) << 4);
  const unsigned smw0 = (unsigned)(w * 512 + l * 4) ^ sw;
  const unsigned smw1 = (unsigned)(w * 512 + 256 + l * 4) ^ sw;

  for (int t = 0; t < 512; ++t) {
    // --- top: prefetch thr and Xp for THIS step (slot t+1; overwritten below B2) ---
    const float4 thA = *(const float4*)(vt + vo);
    const float4 thB = *(const float4*)(vt + vo + 256);
    const float4 xpA = *(const float4*)(zt + vo);
    const float4 xpB = *(const float4*)(zt + vo + 256);

    // --- v update, tanh, int8 quantize (tid-linear, all lanes useful) ---
    unsigned pA = 0, pB = 0;
#pragma unroll
    for (int i = 0; i < 8; ++i) {
      const float add = ((zb >> i) & 1u) ? 0.1f : 0.0f;
      v[i] = __builtin_fmaf(0.9f, v[i], add);
      const float s = fast_tanh_pos(v[i]);
      const int q = __float2int_rn(s * SC_S);     // 0..127
      if (i < 4) pA |= ((unsigned)q) << (8 * i);
      else       pB |= ((unsigned)q) << (8 * (i - 4));
    }
    *(unsigned*)(s_sm + smw0) = pA;
    *(unsigned*)(s_sm + smw1) = pB;

    // --- B1: LDS-only barrier (don't drain the global prefetches) ---
    asm volatile("s_waitcnt lgkmcnt(0)\n\ts_barrier" ::: "memory");

    // --- MFMA: lamb_rec[8b x 64n] over K=512, int8 ---
    i32x4 a0 = {0,0,0,0}, a1 = {0,0,0,0}, a2 = {0,0,0,0}, a3 = {0,0,0,0};
#pragma unroll
    for (int kt = 0; kt < 8; ++kt) {
      const i32x4 af = *(const i32x4*)(s_sm +
          (((unsigned)(llo * 512 + kt * 64 + lhi * 16)) ^ ((unsigned)((llo & 7) << 4))));
      a0 = __builtin_amdgcn_mfma_i32_16x16x64_i8(af, ji[0][kt], a0, 0, 0, 0);
      a1 = __builtin_amdgcn_mfma_i32_16x16x64_i8(af, ji[1][kt], a1, 0, 0, 0);
      a2 = __builtin_amdgcn_mfma_i32_16x16x64_i8(af, ji[2][kt], a2, 0, 0, 0);
      a3 = __builtin_amdgcn_mfma_i32_16x16x64_i8(af, ji[3][kt], a3, 0, 0, 0);
    }
    // valid C rows 0-7 live in lanes lhi<2; redistribute raw i32 via LDS
    if (lhi < 2) {
      const int rb = lhi * 4, cb = w * 64 + llo;
#pragma unroll
      for (int r = 0; r < 4; ++r) {
        s_lam[(rb + r) * 512 + cb]      = a0[r];
        s_lam[(rb + r) * 512 + cb + 16] = a1[r];
        s_lam[(rb + r) * 512 + cb + 32] = a2[r];
        s_lam[(rb + r) * 512 + cb + 48] = a3[r];
      }
    }
    __syncthreads();   // B2: lam ready; also drains top prefetches before slot overwrite

    // --- epilogue (tid-linear): lamb = acc*SC + Xp; store; spike compare ---
    const int* lp = s_lam + w * 512 + l * 4;
    const i32x4 LA = *(const i32x4*)lp;
    const i32x4 LB = *(const i32x4*)(lp + 256);
    float4 lamA, lamB;
    lamA.x = __builtin_fmaf((float)LA[0], SC, xpA.x);
    lamA.y = __builtin_fmaf((float)LA[1], SC, xpA.y);
    lamA.z = __builtin_fmaf((float)LA[2], SC, xpA.z);
    lamA.w = __builtin_fmaf((float)LA[3], SC, xpA.w);
    lamB.x = __builtin_fmaf((float)LB[0], SC, xpB.x);
    lamB.y = __builtin_fmaf((float)LB[1], SC, xpB.y);
    lamB.z = __builtin_fmaf((float)LB[2], SC, xpB.z);
    lamB.w = __builtin_fmaf((float)LB[3], SC, xpB.w);
    *(float4*)(zt + vo)       = lamA;
    *(float4*)(zt + vo + 256) = lamB;
    zb  = (lamA.x > thA.x ? 1u : 0u)  | (lamA.y > thA.y ? 2u : 0u)
        | (lamA.z > thA.z ? 4u : 0u)  | (lamA.w > thA.w ? 8u : 0u)
        | (lamB.x > thB.x ? 16u : 0u) | (lamB.y > thB.y ? 32u : 0u)
        | (lamB.z > thB.z ? 64u : 0u) | (lamB.w > thB.w ? 128u : 0u);
    // Force the v-store to be ordered after the thA/thB loads completed (zb
    // depends on them); route the store address through (zb & 0) == 0 via asm
    // so the compiler cannot break the dependency.
    unsigned zzero;
    asm("v_and_b32 %0, 0, %1" : "=v"(zzero) : "v"(zb));
    float* vdst = vt + vo + zzero;
    float4 vA, vB;
    vA.x = v[0]; vA.y = v[1]; vA.z = v[2]; vA.w = v[3];
    vB.x = v[4]; vB.y = v[5]; vB.z = v[6]; vB.w = v[7];
    *(float4*)(vdst)       = vA;
    *(float4*)(vdst + 256) = vB;
    vo += 512;
  }
}

// ---------------- out = lamb @ W^T (split bf16) ----------------
__launch_bounds__(256)
__global__ void out_kernel(const unsigned char* __restrict__ ws,
                           const float* __restrict__ zt, float* __restrict__ outp) {
  __shared__ short Lh[64 * 520];
  __shared__ short Ll[64 * 520];
  const unsigned short* wh = (const unsigned short*)(ws + OFF_WH);
  const unsigned short* wl = (const unsigned short*)(ws + OFF_WL);
  const int m0 = blockIdx.x * 64;
  const int tid = threadIdx.x;
  for (int i = tid; i < 64 * 128; i += 256) {
    const int r = i >> 7, kq = i & 127;
    const int bt = m0 + r, b = bt >> 9, t = bt & 511;
    const float4 x4 = *(const float4*)(zt + ((size_t)b * 513 + t + 1) * 512 + kq * 4);
    short4 h4, l4; unsigned short h;
    h = f2bf(x4.x); h4.x = (short)h; l4.x = (short)f2bf(x4.x - bf2f(h));
    h = f2bf(x4.y); h4.y = (short)h; l4.y = (short)f2bf(x4.y - bf2f(h));
    h = f2bf(x4.z); h4.z = (short)h; l4.z = (short)f2bf(x4.z - bf2f(h));
    h = f2bf(x4.w); h4.w = (short)h; l4.w = (short)f2bf(x4.w - bf2f(h));
    *(short4*)(&Lh[r * 520 + kq * 4]) = h4;
    *(short4*)(&Ll[r * 520 + kq * 4]) = l4;
  }
  __syncthreads();
  const int w = tid >> 6, l = tid & 63, lhi = l >> 4, llo = l & 15;
  const int rowA = 16 * w + llo;
  f32x4 a0={0,0,0,0},a1={0,0,0,0},a2={0,0,0,0},a3={0,0,0,0},
        a4={0,0,0,0},a5={0,0,0,0},a6={0,0,0,0},a7={0,0,0,0};
#pragma unroll
  for (int kt = 0; kt < 16; ++kt) {
    const short8x ah = *(const short8x*)(&Lh[rowA * 520 + kt * 32 + lhi * 8]);
    const short8x al = *(const short8x*)(&Ll[rowA * 520 + kt * 32 + lhi * 8]);
#define OT(TI, ACC) { \
    const size_t bi = ((size_t)((kt * 4 + lhi) * 128 + TI * 16 + llo)) * 8; \
    const short8x bh = *(const short8x*)(wh + bi); \
    const short8x bl = *(const short8x*)(wl + bi); \
    ACC = __builtin_amdgcn_mfma_f32_16x16x32_bf16(ah, bh, ACC, 0, 0, 0); \
    ACC = __builtin_amdgcn_mfma_f32_16x16x32_bf16(al, bh, ACC, 0, 0, 0); \
    ACC = __builtin_amdgcn_mfma_f32_16x16x32_bf16(ah, bl, ACC, 0, 0, 0); }
    OT(0, a0) OT(1, a1) OT(2, a2) OT(3, a3) OT(4, a4) OT(5, a5) OT(6, a6) OT(7, a7)
#undef OT
  }
#pragma unroll
  for (int r = 0; r < 4; ++r) {
    const int bt = m0 + 16 * w + lhi * 4 + r;
    float* o = outp + (size_t)bt * 128 + llo;
    o[0]  = a0[r]; o[16] = a1[r]; o[32] = a2[r]; o[48] = a3[r];
    o[64] = a4[r]; o[80] = a5[r]; o[96] = a6[r]; o[112] = a7[r];
  }
}

// ---------------- zfin: z = (lamb > thr(u)), overwrites zt slots ----------------
__global__ void zfin_kernel(const float* __restrict__ U, float* __restrict__ zt) {
  const size_t base = ((size_t)blockIdx.x * 256 + threadIdx.x) * 4;  // grid 32768
  const int b = (int)(base >> 18);
  const int t = (int)((base >> 9) & 511);
  const int n = (int)(base & 511);
  float* zp = zt + ((size_t)b * 513 + t + 1) * 512 + n;
  const float4 lam = *(const float4*)zp;
  const float4 uu = *(const float4*)(U + base);
  float4 zv;
  zv.x = (lam.x > thr_of(uu.x)) ? 1.0f : 0.0f;
  zv.y = (lam.y > thr_of(uu.y)) ? 1.0f : 0.0f;
  zv.z = (lam.z > thr_of(uu.z)) ? 1.0f : 0.0f;
  zv.w = (lam.w > thr_of(uu.w)) ? 1.0f : 0.0f;
  *(float4*)zp = zv;
}

extern "C" void kernel_launch(void* const* d_in, const int* in_sizes, int n_in,
                              void* d_out, int out_size, void* d_ws, size_t ws_size,
                              hipStream_t stream) {
  const float* X  = (const float*)d_in[0];   // inputs [128,512,128]
  const float* U  = (const float*)d_in[1];   // rand_u [128,512,512]
  const float* J  = (const float*)d_in[2];   // [512,512]
  const float* Bw = (const float*)d_in[3];   // [512,128]
  const float* W  = (const float*)d_in[4];   // [128,512]
  float* vt = (float*)d_out;
  float* zt = vt + (size_t)128 * 513 * 512;
  float* op = vt + (size_t)2 * 128 * 513 * 512;
  unsigned char* ws = (unsigned char*)d_ws;
  init_kernel<<<256, 256, 0, stream>>>(vt, zt);
  pack_kernel<<<128, 256, 0, stream>>>(J, Bw, W, ws);
  uth_kernel<<<32768, 256, 0, stream>>>(U, vt);
  xp_kernel<<<dim3(1024, 8), 256, 0, stream>>>(X, ws, zt);
  recur_kernel<<<16, 512, 0, stream>>>(ws, vt, zt);
  out_kernel<<<1024, 256, 0, stream>>>(ws, zt, op);
  zfin_kernel<<<32768, 256, 0, stream>>>(U, zt);
}

// Round 4
// 1014.396 us; speedup vs baseline: 3.4192x; 1.2154x over previous
//
#include <hip/hip_runtime.h>

// RSNN forward: B=128, T=512, IN=128, N=512, OUT=128, fp32 in/out.
// d_out = [vt (128*513*512) | zt (128*513*512) | out (128*512*128)] fp32.
//
// Pipeline (all regions double-used, stream-ordered):
//  1. jwm:  G = W@J (fp32 [128,512]), M = W@Bw (fp32 [128,128])  -> ws
//  2. pack: J->i8 MFMA frags; Bw->bf16 hi/lo frags; G,M->bf16 frags -> ws
//  3. xpd:  Xp = X@Bw^T (split-bf16 MFMA); D = thr(U) - Xp -> vt region (fp32)
//  4. recur: 128 WGs x 1 batch; J i8 in VGPRs (asm-pinned); per step:
//            s=tanh(v) quantized -> LDS -> i8 MFMA -> lam*SC > D -> z byte
//            writes ONLY z8 bytes -> out region. No other I/O in the loop.
//  5. vsz:  per b: re-scan z8 -> exact vt, zt floats; s=tanh(v) bf16 tile;
//            out = s@G^T + X@M^T via MFMA, overwriting z8 chunk-in-place.

typedef __attribute__((ext_vector_type(8))) short short8x;
typedef __attribute__((ext_vector_type(4))) float f32x4;
typedef __attribute__((ext_vector_type(4))) int i32x4;

// ---- workspace layout (bytes), total 1,015,808 ----
#define OFF_JQK  (0u)        // J i8 frags: 16384 * 16B = 262144
#define OFF_BWH  (262144u)   // Bw hi bf16 frags: 131072
#define OFF_BWL  (393216u)
#define OFF_G    (524288u)   // G fp32 [128][512] = 262144
#define OFF_M    (786432u)   // M fp32 [128][128] = 65536
#define OFF_GPK  (851968u)   // G bf16 frags: 8192*16 = 131072
#define OFF_MPK  (983040u)   // M bf16 frags: 2048*16 = 32768

#define SC_J 640.0f
#define SC_S 166.0f

__device__ __forceinline__ unsigned short f2bf(float f) {
  union { float f; unsigned u; } a; a.f = f;
  unsigned r = a.u + 0x7FFFu + ((a.u >> 16) & 1u);   // RNE bf16
  return (unsigned short)(r >> 16);
}
__device__ __forceinline__ float bf2f(unsigned short h) {
  union { unsigned u; float f; } a; a.u = ((unsigned)h) << 16;
  return a.f;
}
// spike(p>u) <=> lamb > thr(u), thr = 0.4 + 4*logit(u)
__device__ __forceinline__ float thr_of(float u) {
  return __builtin_fmaf(4.0f, __logf(u / (1.0f - u)), 0.4f);
}
__device__ __forceinline__ float fast_tanh_pos(float x) {  // x >= 0 here
  const float e2 = __expf(x + x);
  return 1.0f - 2.0f / (e2 + 1.0f);
}

// ---------------- 1. jwm: G = W@J, M = W@Bw (fp32) ----------------
__launch_bounds__(512)
__global__ void jwm_kernel(const float* __restrict__ J, const float* __restrict__ Bw,
                           const float* __restrict__ W, unsigned char* __restrict__ ws) {
  __shared__ float wrow[512];
  const int o = blockIdx.x;          // 0..127
  const int tid = threadIdx.x;
  wrow[tid] = W[(size_t)o * 512 + tid];
  __syncthreads();
  const int k = tid;                 // 0..511
  const int i = tid & 127;
  float g = 0.0f, m = 0.0f;
  for (int n = 0; n < 512; ++n) {
    const float wv = wrow[n];
    g = __builtin_fmaf(wv, J[(size_t)n * 512 + k], g);
    m = __builtin_fmaf(wv, Bw[(size_t)n * 128 + i], m);
  }
  ((float*)(ws + OFF_G))[(size_t)o * 512 + k] = g;
  if (tid < 128) ((float*)(ws + OFF_M))[(size_t)o * 128 + i] = m;
}

// ---------------- 2. pack: JQK i8 | Bw hi/lo | GPK | MPK ----------------
// id ranges: [0,16384) JQK | [16384,24576) Bw | [24576,32768) GPK | [32768,34816) MPK
__global__ void pack_kernel(const float* __restrict__ J, const float* __restrict__ Bw,
                            unsigned char* __restrict__ ws) {
  const int id = blockIdx.x * 256 + threadIdx.x;   // grid 136 -> 34816
  if (id < 16384) {
    const int idx = id;                 // (kt*4+lhi)*512 + n
    const int n = idx & 511, kg = idx >> 9, k0 = kg * 16;
    unsigned dw[4];
#pragma unroll
    for (int d = 0; d < 4; ++d) {
      unsigned x = 0;
#pragma unroll
      for (int p = 0; p < 4; ++p) {
        const float jv = J[(size_t)n * 512 + k0 + 4 * d + p];
        int q = __float2int_rn(jv * SC_J);
        q = q > 127 ? 127 : (q < -127 ? -127 : q);
        x |= ((unsigned)(q & 255)) << (8 * p);
      }
      dw[d] = x;
    }
    uint4 out; out.x = dw[0]; out.y = dw[1]; out.z = dw[2]; out.w = dw[3];
    ((uint4*)(ws + OFF_JQK))[idx] = out;
  } else if (id < 24576) {
    const int idx = id - 16384;         // (kt*4+g)*512 + n, kt<4
    const int n = idx & 511, kg = idx >> 9, k0 = kg * 8;
    unsigned short* bwh = (unsigned short*)(ws + OFF_BWH);
    unsigned short* bwl = (unsigned short*)(ws + OFF_BWL);
    for (int e = 0; e < 8; ++e) {
      const float x = Bw[(size_t)n * 128 + k0 + e];
      const unsigned short h = f2bf(x);
      bwh[(size_t)idx * 8 + e] = h;
      bwl[(size_t)idx * 8 + e] = f2bf(x - bf2f(h));
    }
  } else if (id < 32768) {
    const int idx = id - 24576;         // (kt*4+g)*128 + o, kt<16
    const int o = idx & 127, kg = idx >> 7, k0 = kg * 8;
    const float* G = (const float*)(ws + OFF_G);
    unsigned short* gpk = (unsigned short*)(ws + OFF_GPK);
    for (int e = 0; e < 8; ++e) gpk[(size_t)idx * 8 + e] = f2bf(G[(size_t)o * 512 + k0 + e]);
  } else {
    const int idx = id - 32768;         // (kt*4+g)*128 + o, kt<4
    const int o = idx & 127, kg = idx >> 7, k0 = kg * 8;
    const float* M = (const float*)(ws + OFF_M);
    unsigned short* mpk = (unsigned short*)(ws + OFF_MPK);
    for (int e = 0; e < 8; ++e) mpk[(size_t)idx * 8 + e] = f2bf(M[(size_t)o * 128 + k0 + e]);
  }
}

// ---------------- 3. xpd: Xp = X@Bw^T (split bf16), D = thr(U) - Xp ----------------
__launch_bounds__(256)
__global__ void xpd_kernel(const float* __restrict__ X, const float* __restrict__ U,
                           const unsigned char* __restrict__ ws, float* __restrict__ Dbuf) {
  __shared__ short Ah[64 * 136];
  __shared__ short Al[64 * 136];
  const unsigned short* bwh = (const unsigned short*)(ws + OFF_BWH);
  const unsigned short* bwl = (const unsigned short*)(ws + OFF_BWL);
  const int m0 = blockIdx.x * 64;   // bt rows
  const int n0 = blockIdx.y * 64;   // neuron cols
  const int tid = threadIdx.x;
  for (int i = tid; i < 64 * 32; i += 256) {
    const int r = i >> 5, kq = i & 31;
    const float4 x4 = *(const float4*)(X + (size_t)(m0 + r) * 128 + kq * 4);
    short4 h4, l4; unsigned short h;
    h = f2bf(x4.x); h4.x = (short)h; l4.x = (short)f2bf(x4.x - bf2f(h));
    h = f2bf(x4.y); h4.y = (short)h; l4.y = (short)f2bf(x4.y - bf2f(h));
    h = f2bf(x4.z); h4.z = (short)h; l4.z = (short)f2bf(x4.z - bf2f(h));
    h = f2bf(x4.w); h4.w = (short)h; l4.w = (short)f2bf(x4.w - bf2f(h));
    *(short4*)(&Ah[r * 136 + kq * 4]) = h4;
    *(short4*)(&Al[r * 136 + kq * 4]) = l4;
  }
  __syncthreads();
  const int w = tid >> 6, l = tid & 63, lhi = l >> 4, llo = l & 15;
  const int rowA = 16 * w + llo;
  f32x4 a0 = {0,0,0,0}, a1 = {0,0,0,0}, a2 = {0,0,0,0}, a3 = {0,0,0,0};
#pragma unroll
  for (int kt = 0; kt < 4; ++kt) {
    const short8x ah = *(const short8x*)(&Ah[rowA * 136 + kt * 32 + lhi * 8]);
    const short8x al = *(const short8x*)(&Al[rowA * 136 + kt * 32 + lhi * 8]);
#define XT(TI, ACC) { \
    const size_t bi = ((size_t)((kt * 4 + lhi) * 512 + n0 + TI * 16 + llo)) * 8; \
    const short8x bh = *(const short8x*)(bwh + bi); \
    const short8x bl = *(const short8x*)(bwl + bi); \
    ACC = __builtin_amdgcn_mfma_f32_16x16x32_bf16(ah, bh, ACC, 0, 0, 0); \
    ACC = __builtin_amdgcn_mfma_f32_16x16x32_bf16(al, bh, ACC, 0, 0, 0); \
    ACC = __builtin_amdgcn_mfma_f32_16x16x32_bf16(ah, bl, ACC, 0, 0, 0); }
    XT(0, a0) XT(1, a1) XT(2, a2) XT(3, a3)
#undef XT
  }
  const int n = n0 + llo;
#pragma unroll
  for (int r = 0; r < 4; ++r) {
    const int bt = m0 + 16 * w + lhi * 4 + r;
    const float* urow = U + (size_t)bt * 512;
    float* drow = Dbuf + (size_t)bt * 512;
    drow[n]      = thr_of(urow[n])      - a0[r];
    drow[n + 16] = thr_of(urow[n + 16]) - a1[r];
    drow[n + 32] = thr_of(urow[n + 32]) - a2[r];
    drow[n + 48] = thr_of(urow[n + 48]) - a3[r];
  }
}

// ---------------- 4. recur: 128 WGs x 512 thr, 1 batch/WG ----------------
// Wave w owns post-neurons [w*64,(w+1)*64). J i8 VGPR-resident via volatile asm
// loads (not rematerializable). State v is tid-linear (n = tid). Per step:
// quantize s -> s_sm -> B1 -> MFMA (B-frag lane-broadcast) -> s_lam -> B2 ->
// z = lam*SC > D -> z8 byte to out region. Raw barriers keep prefetch in flight.
__launch_bounds__(512, 2)
__global__ void recur_kernel(const unsigned char* __restrict__ ws,
                             const float* __restrict__ Dbuf,
                             unsigned char* __restrict__ z8) {
  __shared__ unsigned char s_sm[512];
  __shared__ int s_lam[512];
  const int b = blockIdx.x;
  const int tid = threadIdx.x;
  const int w = tid >> 6, l = tid & 63;
  const int lhi = l >> 4, llo = l & 15;

  // J fragments: frag idx (kt*4+lhi)*512 + (w*64 + j*16 + llo), 16B each.
  i32x4 ji[4][8];
#pragma unroll
  for (int kt = 0; kt < 8; ++kt) {
    const unsigned base = (unsigned)(kt * 4 + lhi) * 512u + (unsigned)(w * 64 + llo);
#pragma unroll
    for (int j = 0; j < 4; ++j) {
      const unsigned char* p = ws + OFF_JQK + (size_t)(base + 16u * j) * 16u;
      asm volatile("global_load_dwordx4 %0, %1, off" : "=v"(ji[j][kt]) : "v"(p));
    }
  }
  asm volatile("s_waitcnt vmcnt(0)" ::: "memory");

  const float SC = 1.0f / (SC_J * SC_S);
  float v = 0.0f;
  unsigned zprev = 0u;
  const size_t dbase = ((size_t)b * 512) * 512 + (size_t)tid;
  float dc = Dbuf[dbase];
  float dn = Dbuf[dbase + 512];
  unsigned char* zwg = z8 + ((size_t)b * 512) * 512;

  for (int t = 0; t < 512; ++t) {
    // --- A: s = tanh(v) quantize, pack 4 bytes, LDS write ---
    v = __builtin_fmaf(0.9f, v, zprev ? 0.1f : 0.0f);
    const float s = fast_tanh_pos(v);
    unsigned q = (unsigned)__float2int_rn(s * SC_S);      // 0..127
    q |= ((unsigned)__shfl_down((int)q, 1)) << 8;
    q |= ((unsigned)__shfl_down((int)q, 2)) << 16;
    if ((l & 3) == 0) *(unsigned*)(s_sm + (tid & ~3)) = q;
    // --- B1 (LDS only; global prefetches stay in flight) ---
    asm volatile("s_waitcnt lgkmcnt(0)\n\ts_barrier" ::: "memory");
    // --- MFMA: lam[n] over K=512; B-frag is lane-broadcast (col 0 valid) ---
    i32x4 a0 = {0,0,0,0}, a1 = {0,0,0,0}, a2 = {0,0,0,0}, a3 = {0,0,0,0};
#pragma unroll
    for (int kt = 0; kt < 8; ++kt) {
      const i32x4 bf = *(const i32x4*)(s_sm + kt * 64 + lhi * 16);
      a0 = __builtin_amdgcn_mfma_i32_16x16x64_i8(ji[0][kt], bf, a0, 0, 0, 0);
      a1 = __builtin_amdgcn_mfma_i32_16x16x64_i8(ji[1][kt], bf, a1, 0, 0, 0);
      a2 = __builtin_amdgcn_mfma_i32_16x16x64_i8(ji[2][kt], bf, a2, 0, 0, 0);
      a3 = __builtin_amdgcn_mfma_i32_16x16x64_i8(ji[3][kt], bf, a3, 0, 0, 0);
    }
    // C col 0 lives in lanes llo==0; rows lhi*4+r of each 16-tile
    if (llo == 0) {
      *(i32x4*)(s_lam + w * 64 +  0 + lhi * 4) = a0;
      *(i32x4*)(s_lam + w * 64 + 16 + lhi * 4) = a1;
      *(i32x4*)(s_lam + w * 64 + 32 + lhi * 4) = a2;
      *(i32x4*)(s_lam + w * 64 + 48 + lhi * 4) = a3;
    }
    // --- B2 ---
    asm volatile("s_waitcnt lgkmcnt(0)\n\ts_barrier" ::: "memory");
    // --- F: spike compare (tid-linear), z8 write, next-D prefetch ---
    const float lam = (float)s_lam[tid] * SC;
    const unsigned z = (lam > dc) ? 1u : 0u;
    unsigned zq = z;
    zq |= ((unsigned)__shfl_down((int)zq, 1)) << 8;
    zq |= ((unsigned)__shfl_down((int)zq, 2)) << 16;
    if ((l & 3) == 0) *(unsigned*)(zwg + ((size_t)t << 9) + (tid & ~3)) = zq;
    zprev = z;
    dc = dn;
    if (t < 510) dn = Dbuf[dbase + ((size_t)(t + 2) << 9)];
  }
}

// ---------------- 5. vsz: scan z8 -> vt/zt floats + out = s@G^T + X@M^T ----------------
// Block per b. Per 64-step chunk: stage z8 chunk + X chunk -> LDS; scan (exact
// fp32 recurrence) writing vt/zt and bf16 s-tile; MFMA [64t x 128o] over
// K=512 (G) + K=128 (M); overwrite the consumed z8 chunk in-place with out.
__launch_bounds__(512)
__global__ void vsz_kernel(const float* __restrict__ X, const unsigned char* __restrict__ ws,
                           float* __restrict__ vt, float* __restrict__ zt,
                           float* __restrict__ op) {
  __shared__ unsigned zl[8192];              // 32KB z8 chunk
  __shared__ unsigned short sl[64 * 520];    // s bf16 [64 t][512 n], pad 8
  __shared__ unsigned short xl[64 * 136];    // X bf16 [64 t][128 i], pad 8
  const int b = blockIdx.x;
  const int tid = threadIdx.x;
  const int w = tid >> 6, l = tid & 63, lhi = l >> 4, llo = l & 15;
  const unsigned short* gpk = (const unsigned short*)(ws + OFF_GPK);
  const unsigned short* mpk = (const unsigned short*)(ws + OFF_MPK);
  const unsigned char* z8 = (const unsigned char*)op;

  float v = 0.0f;
  unsigned zprev = 0u;
  // t = 0 slots
  vt[((size_t)b * 513) * 512 + tid] = 0.0f;
  zt[((size_t)b * 513) * 512 + tid] = 0.0f;

  for (int c = 0; c < 8; ++c) {
    // --- stage z8 chunk + X chunk ---
    const uint4* src = (const uint4*)(z8 + (size_t)b * 262144 + (size_t)c * 32768);
#pragma unroll
    for (int i = 0; i < 4; ++i) ((uint4*)zl)[i * 512 + tid] = src[i * 512 + tid];
#pragma unroll
    for (int i = 0; i < 4; ++i) {
      const int idx = i * 512 + tid;            // 0..2047
      const int r = idx >> 5, c4 = (idx & 31) * 4;
      const float4 x4 = *(const float4*)(X + ((size_t)b * 512 + c * 64 + r) * 128 + c4);
      short4 h4;
      h4.x = (short)f2bf(x4.x); h4.y = (short)f2bf(x4.y);
      h4.z = (short)f2bf(x4.z); h4.w = (short)f2bf(x4.w);
      *(short4*)(xl + r * 136 + c4) = h4;
    }
    __syncthreads();
    // --- scan 64 steps (thread owns n = tid) ---
    const unsigned char* zb = (const unsigned char*)zl;
    float* vrow = vt + ((size_t)b * 513 + c * 64 + 1) * 512 + tid;
    float* zrow = zt + ((size_t)b * 513 + c * 64 + 1) * 512 + tid;
#pragma unroll 8
    for (int tl = 0; tl < 64; ++tl) {
      v = __builtin_fmaf(0.9f, v, zprev ? 0.1f : 0.0f);
      const unsigned z = zb[tl * 512 + tid];
      vrow[(size_t)tl * 512] = v;
      zrow[(size_t)tl * 512] = z ? 1.0f : 0.0f;
      sl[tl * 520 + tid] = f2bf(fast_tanh_pos(v));
      zprev = z;
    }
    __syncthreads();
    // --- MFMA: C[64 t][128 o]; wave w: m-tile = w>>1, o-tiles (w&1)*4 + 0..3 ---
    const int m = w >> 1, oh = (w & 1) * 4;
    f32x4 a0 = {0,0,0,0}, a1 = {0,0,0,0}, a2 = {0,0,0,0}, a3 = {0,0,0,0};
#pragma unroll
    for (int kt = 0; kt < 16; ++kt) {
      const short8x A = *(const short8x*)(sl + (m * 16 + llo) * 520 + kt * 32 + lhi * 8);
#define GT(TI, ACC) { \
      const short8x B = *(const short8x*)(gpk + ((size_t)((kt * 4 + lhi) * 128 + (oh + TI) * 16 + llo)) * 8); \
      ACC = __builtin_amdgcn_mfma_f32_16x16x32_bf16(A, B, ACC, 0, 0, 0); }
      GT(0, a0) GT(1, a1) GT(2, a2) GT(3, a3)
#undef GT
    }
#pragma unroll
    for (int kt = 0; kt < 4; ++kt) {
      const short8x A = *(const short8x*)(xl + (m * 16 + llo) * 136 + kt * 32 + lhi * 8);
#define MT(TI, ACC) { \
      const short8x B = *(const short8x*)(mpk + ((size_t)((kt * 4 + lhi) * 128 + (oh + TI) * 16 + llo)) * 8); \
      ACC = __builtin_amdgcn_mfma_f32_16x16x32_bf16(A, B, ACC, 0, 0, 0); }
      MT(0, a0) MT(1, a1) MT(2, a2) MT(3, a3)
#undef MT
    }
    // --- overwrite consumed z8 chunk with out floats ---
    float* obase = op + ((size_t)b * 512 + c * 64 + m * 16 + lhi * 4) * 128 + llo;
#pragma unroll
    for (int r = 0; r < 4; ++r) {
      float* orow = obase + (size_t)r * 128;
      orow[(oh + 0) * 16] = a0[r];
      orow[(oh + 1) * 16] = a1[r];
      orow[(oh + 2) * 16] = a2[r];
      orow[(oh + 3) * 16] = a3[r];
    }
    __syncthreads();   // protect zl/sl/xl before next chunk's staging
  }
}

extern "C" void kernel_launch(void* const* d_in, const int* in_sizes, int n_in,
                              void* d_out, int out_size, void* d_ws, size_t ws_size,
                              hipStream_t stream) {
  const float* X  = (const float*)d_in[0];   // inputs [128,512,128]
  const float* U  = (const float*)d_in[1];   // rand_u [128,512,512]
  const float* J  = (const float*)d_in[2];   // [512,512]
  const float* Bw = (const float*)d_in[3];   // [512,128]
  const float* W  = (const float*)d_in[4];   // [128,512]
  float* vt = (float*)d_out;
  float* zt = vt + (size_t)128 * 513 * 512;
  float* op = vt + (size_t)2 * 128 * 513 * 512;
  unsigned char* ws = (unsigned char*)d_ws;
  float* Dbuf = vt;                                   // D fp32 [bt][n] in vt region
  unsigned char* z8 = (unsigned char*)op;             // z bytes in out region

  jwm_kernel<<<128, 512, 0, stream>>>(J, Bw, W, ws);
  pack_kernel<<<136, 256, 0, stream>>>(J, Bw, ws);
  xpd_kernel<<<dim3(1024, 8), 256, 0, stream>>>(X, U, ws, Dbuf);
  recur_kernel<<<128, 512, 0, stream>>>(ws, Dbuf, z8);
  vsz_kernel<<<128, 512, 0, stream>>>(X, ws, vt, zt, op);
}

// Round 5
// 806.894 us; speedup vs baseline: 4.2985x; 1.2572x over previous
//
#include <hip/hip_runtime.h>

// RSNN forward: B=128, T=512, IN=128, N=512, OUT=128, fp32 in/out.
// d_out = [vt (128*513*512) | zt (128*513*512) | out (128*512*128)] fp32.
//
// Pipeline (all regions double-used, stream-ordered):
//  1. jwm:  G = W@J (fp32 [128,512]), M = W@Bw (fp32 [128,128])  -> ws
//  2. pack: J->i8 MFMA frags; Bw->bf16 hi/lo frags; G,M->bf16 frags -> ws
//  3. xpd:  Xp = X@Bw^T (split-bf16 MFMA); D = thr(U) - Xp -> vt region (fp32)
//  4. recur: 128 WGs x 1 batch; J i8 in VGPRs/AGPRs (asm-pinned loads);
//            per step: s=tanh(v) -> i8 byte -> LDS (dbuf) -> ONE barrier ->
//            i8 MFMA -> wave-local LDS lam redistribute (lgkmcnt only) ->
//            z = lam*SC > D(reg, prefetched 8 ahead) -> z byte -> out region.
//  5. vsz:  per b: re-scan z8 -> exact vt, zt floats; s=tanh(v) bf16 tile;
//            out = s@G^T + X@M^T via MFMA, overwriting z8 chunk-in-place.

typedef __attribute__((ext_vector_type(8))) short short8x;
typedef __attribute__((ext_vector_type(4))) float f32x4;
typedef __attribute__((ext_vector_type(4))) int i32x4;

// ---- workspace layout (bytes), total 1,015,808 ----
#define OFF_JQK  (0u)        // J i8 frags: 16384 * 16B = 262144
#define OFF_BWH  (262144u)   // Bw hi bf16 frags: 131072
#define OFF_BWL  (393216u)
#define OFF_G    (524288u)   // G fp32 [128][512] = 262144
#define OFF_M    (786432u)   // M fp32 [128][128] = 65536
#define OFF_GPK  (851968u)   // G bf16 frags: 8192*16 = 131072
#define OFF_MPK  (983040u)   // M bf16 frags: 2048*16 = 32768

#define SC_J 640.0f
#define SC_S 166.0f

__device__ __forceinline__ unsigned short f2bf(float f) {
  union { float f; unsigned u; } a; a.f = f;
  unsigned r = a.u + 0x7FFFu + ((a.u >> 16) & 1u);   // RNE bf16
  return (unsigned short)(r >> 16);
}
__device__ __forceinline__ float bf2f(unsigned short h) {
  union { unsigned u; float f; } a; a.u = ((unsigned)h) << 16;
  return a.f;
}
// spike(p>u) <=> lamb > thr(u), thr = 0.4 + 4*logit(u)
__device__ __forceinline__ float thr_of(float u) {
  return __builtin_fmaf(4.0f, __logf(u / (1.0f - u)), 0.4f);
}
__device__ __forceinline__ float fast_tanh_pos(float x) {  // x >= 0 here
  const float e2 = __expf(x + x);
  return 1.0f - 2.0f / (e2 + 1.0f);
}

// ---------------- 1. jwm: G = W@J, M = W@Bw (fp32) ----------------
__launch_bounds__(512)
__global__ void jwm_kernel(const float* __restrict__ J, const float* __restrict__ Bw,
                           const float* __restrict__ W, unsigned char* __restrict__ ws) {
  __shared__ float wrow[512];
  const int o = blockIdx.x;          // 0..127
  const int tid = threadIdx.x;
  wrow[tid] = W[(size_t)o * 512 + tid];
  __syncthreads();
  const int k = tid;                 // 0..511
  const int i = tid & 127;
  float g = 0.0f, m = 0.0f;
  for (int n = 0; n < 512; ++n) {
    const float wv = wrow[n];
    g = __builtin_fmaf(wv, J[(size_t)n * 512 + k], g);
    m = __builtin_fmaf(wv, Bw[(size_t)n * 128 + i], m);
  }
  ((float*)(ws + OFF_G))[(size_t)o * 512 + k] = g;
  if (tid < 128) ((float*)(ws + OFF_M))[(size_t)o * 128 + i] = m;
}

// ---------------- 2. pack: JQK i8 | Bw hi/lo | GPK | MPK ----------------
// id ranges: [0,16384) JQK | [16384,24576) Bw | [24576,32768) GPK | [32768,34816) MPK
__global__ void pack_kernel(const float* __restrict__ J, const float* __restrict__ Bw,
                            unsigned char* __restrict__ ws) {
  const int id = blockIdx.x * 256 + threadIdx.x;   // grid 136 -> 34816
  if (id < 16384) {
    const int idx = id;                 // (kt*4+lhi)*512 + n
    const int n = idx & 511, kg = idx >> 9, k0 = kg * 16;
    unsigned dw[4];
#pragma unroll
    for (int d = 0; d < 4; ++d) {
      unsigned x = 0;
#pragma unroll
      for (int p = 0; p < 4; ++p) {
        const float jv = J[(size_t)n * 512 + k0 + 4 * d + p];
        int q = __float2int_rn(jv * SC_J);
        q = q > 127 ? 127 : (q < -127 ? -127 : q);
        x |= ((unsigned)(q & 255)) << (8 * p);
      }
      dw[d] = x;
    }
    uint4 out; out.x = dw[0]; out.y = dw[1]; out.z = dw[2]; out.w = dw[3];
    ((uint4*)(ws + OFF_JQK))[idx] = out;
  } else if (id < 24576) {
    const int idx = id - 16384;         // (kt*4+g)*512 + n, kt<4
    const int n = idx & 511, kg = idx >> 9, k0 = kg * 8;
    unsigned short* bwh = (unsigned short*)(ws + OFF_BWH);
    unsigned short* bwl = (unsigned short*)(ws + OFF_BWL);
    for (int e = 0; e < 8; ++e) {
      const float x = Bw[(size_t)n * 128 + k0 + e];
      const unsigned short h = f2bf(x);
      bwh[(size_t)idx * 8 + e] = h;
      bwl[(size_t)idx * 8 + e] = f2bf(x - bf2f(h));
    }
  } else if (id < 32768) {
    const int idx = id - 24576;         // (kt*4+g)*128 + o, kt<16
    const int o = idx & 127, kg = idx >> 7, k0 = kg * 8;
    const float* G = (const float*)(ws + OFF_G);
    unsigned short* gpk = (unsigned short*)(ws + OFF_GPK);
    for (int e = 0; e < 8; ++e) gpk[(size_t)idx * 8 + e] = f2bf(G[(size_t)o * 512 + k0 + e]);
  } else {
    const int idx = id - 32768;         // (kt*4+g)*128 + o, kt<4
    const int o = idx & 127, kg = idx >> 7, k0 = kg * 8;
    const float* M = (const float*)(ws + OFF_M);
    unsigned short* mpk = (unsigned short*)(ws + OFF_MPK);
    for (int e = 0; e < 8; ++e) mpk[(size_t)idx * 8 + e] = f2bf(M[(size_t)o * 128 + k0 + e]);
  }
}

// ---------------- 3. xpd: Xp = X@Bw^T (split bf16), D = thr(U) - Xp ----------------
__launch_bounds__(256)
__global__ void xpd_kernel(const float* __restrict__ X, const float* __restrict__ U,
                           const unsigned char* __restrict__ ws, float* __restrict__ Dbuf) {
  __shared__ short Ah[64 * 136];
  __shared__ short Al[64 * 136];
  const unsigned short* bwh = (const unsigned short*)(ws + OFF_BWH);
  const unsigned short* bwl = (const unsigned short*)(ws + OFF_BWL);
  const int m0 = blockIdx.x * 64;   // bt rows
  const int n0 = blockIdx.y * 64;   // neuron cols
  const int tid = threadIdx.x;
  for (int i = tid; i < 64 * 32; i += 256) {
    const int r = i >> 5, kq = i & 31;
    const float4 x4 = *(const float4*)(X + (size_t)(m0 + r) * 128 + kq * 4);
    short4 h4, l4; unsigned short h;
    h = f2bf(x4.x); h4.x = (short)h; l4.x = (short)f2bf(x4.x - bf2f(h));
    h = f2bf(x4.y); h4.y = (short)h; l4.y = (short)f2bf(x4.y - bf2f(h));
    h = f2bf(x4.z); h4.z = (short)h; l4.z = (short)f2bf(x4.z - bf2f(h));
    h = f2bf(x4.w); h4.w = (short)h; l4.w = (short)f2bf(x4.w - bf2f(h));
    *(short4*)(&Ah[r * 136 + kq * 4]) = h4;
    *(short4*)(&Al[r * 136 + kq * 4]) = l4;
  }
  __syncthreads();
  const int w = tid >> 6, l = tid & 63, lhi = l >> 4, llo = l & 15;
  const int rowA = 16 * w + llo;
  f32x4 a0 = {0,0,0,0}, a1 = {0,0,0,0}, a2 = {0,0,0,0}, a3 = {0,0,0,0};
#pragma unroll
  for (int kt = 0; kt < 4; ++kt) {
    const short8x ah = *(const short8x*)(&Ah[rowA * 136 + kt * 32 + lhi * 8]);
    const short8x al = *(const short8x*)(&Al[rowA * 136 + kt * 32 + lhi * 8]);
#define XT(TI, ACC) { \
    const size_t bi = ((size_t)((kt * 4 + lhi) * 512 + n0 + TI * 16 + llo)) * 8; \
    const short8x bh = *(const short8x*)(bwh + bi); \
    const short8x bl = *(const short8x*)(bwl + bi); \
    ACC = __builtin_amdgcn_mfma_f32_16x16x32_bf16(ah, bh, ACC, 0, 0, 0); \
    ACC = __builtin_amdgcn_mfma_f32_16x16x32_bf16(al, bh, ACC, 0, 0, 0); \
    ACC = __builtin_amdgcn_mfma_f32_16x16x32_bf16(ah, bl, ACC, 0, 0, 0); }
    XT(0, a0) XT(1, a1) XT(2, a2) XT(3, a3)
#undef XT
  }
  const int n = n0 + llo;
#pragma unroll
  for (int r = 0; r < 4; ++r) {
    const int bt = m0 + 16 * w + lhi * 4 + r;
    const float* urow = U + (size_t)bt * 512;
    float* drow = Dbuf + (size_t)bt * 512;
    drow[n]      = thr_of(urow[n])      - a0[r];
    drow[n + 16] = thr_of(urow[n + 16]) - a1[r];
    drow[n + 32] = thr_of(urow[n + 32]) - a2[r];
    drow[n + 48] = thr_of(urow[n + 48]) - a3[r];
  }
}

// ---------------- 4. recur: 128 WGs x 512 thr, 1 batch/WG ----------------
// Wave w owns neurons [w*64,(w+1)*64), lane l owns n = w*64+l. J i8 resident
// (volatile asm loads -> unified VGPR/AGPR file). Per step: quantize s ->
// ds_write_b8 into s_sm[t&1] -> ONE barrier -> 32 MFMA -> wave-local lam
// redistribute (ds_write_b128 + lgkmcnt(0), no barrier) -> z compare vs
// register-prefetched D (8 steps ahead) -> z8 byte store.
__launch_bounds__(512, 1)
__global__ void recur_kernel(const unsigned char* __restrict__ ws,
                             const float* __restrict__ Dbuf,
                             unsigned char* __restrict__ z8) {
  __shared__ unsigned char s_sm[2][512];
  __shared__ int lam_s[512];
  const int b = blockIdx.x;
  const int tid = threadIdx.x;
  const int w = tid >> 6, l = tid & 63;
  const int lhi = l >> 4, llo = l & 15;
  const int n = tid;

  // J fragments: frag idx (kt*4+lhi)*512 + (w*64 + j*16 + llo), 16B each.
  i32x4 ji[4][8];
#pragma unroll
  for (int kt = 0; kt < 8; ++kt) {
    const unsigned base = (unsigned)(kt * 4 + lhi) * 512u + (unsigned)(w * 64 + llo);
#pragma unroll
    for (int j = 0; j < 4; ++j) {
      const unsigned char* p = ws + OFF_JQK + (size_t)(base + 16u * j) * 16u;
      asm volatile("global_load_dwordx4 %0, %1, off" : "=v"(ji[j][kt]) : "v"(p));
    }
  }
  asm volatile("s_waitcnt vmcnt(0)" ::: "memory");

  const float SC = 1.0f / (SC_J * SC_S);
  float v = 0.0f;
  unsigned zprev = 0u;
  const float* Dp = Dbuf + (size_t)b * 262144 + n;
  unsigned char* zwg = z8 + (size_t)b * 262144 + n;

  float dc[8], dnx[8];
#pragma unroll
  for (int i = 0; i < 8; ++i) dc[i] = Dp[(size_t)i * 512];

  for (int c = 0; c < 64; ++c) {       // 64 chunks x 8 steps
    const int t0 = c * 8;
    // issue next-chunk D loads (last chunk over-reads stay inside vt region)
#pragma unroll
    for (int i = 0; i < 8; ++i) dnx[i] = Dp[(size_t)(t0 + 8 + i) * 512];
#pragma unroll
    for (int i = 0; i < 8; ++i) {
      const int t = t0 + i;
      // --- A: v update, tanh, i8 quantize, publish to s_sm[t&1] ---
      v = __builtin_fmaf(0.9f, v, zprev ? 0.1f : 0.0f);
      const float s = fast_tanh_pos(v);
      const unsigned q = (unsigned)__float2int_rn(s * SC_S);   // 0..126
      s_sm[t & 1][n] = (unsigned char)q;
      // --- B1: the only barrier this step (LDS drain + barrier) ---
      asm volatile("s_waitcnt lgkmcnt(0)\n\ts_barrier" ::: "memory");
      // --- MFMA: lam[n] over K=512; B-frag lane-broadcast (col 0 valid) ---
      i32x4 a0 = {0,0,0,0}, a1 = {0,0,0,0}, a2 = {0,0,0,0}, a3 = {0,0,0,0};
#pragma unroll
      for (int kt = 0; kt < 8; ++kt) {
        const i32x4 bf = *(const i32x4*)(&s_sm[t & 1][kt * 64 + lhi * 16]);
        a0 = __builtin_amdgcn_mfma_i32_16x16x64_i8(ji[0][kt], bf, a0, 0, 0, 0);
        a1 = __builtin_amdgcn_mfma_i32_16x16x64_i8(ji[1][kt], bf, a1, 0, 0, 0);
        a2 = __builtin_amdgcn_mfma_i32_16x16x64_i8(ji[2][kt], bf, a2, 0, 0, 0);
        a3 = __builtin_amdgcn_mfma_i32_16x16x64_i8(ji[3][kt], bf, a3, 0, 0, 0);
      }
      // --- wave-local redistribute: col 0 lives in lanes llo==0 ---
      if (llo == 0) {
        *(i32x4*)(lam_s + w * 64 +  0 + lhi * 4) = a0;
        *(i32x4*)(lam_s + w * 64 + 16 + lhi * 4) = a1;
        *(i32x4*)(lam_s + w * 64 + 32 + lhi * 4) = a2;
        *(i32x4*)(lam_s + w * 64 + 48 + lhi * 4) = a3;
      }
      asm volatile("s_waitcnt lgkmcnt(0)" ::: "memory");   // same-wave order
      // --- F: spike compare, z8 byte store ---
      const float lam = (float)lam_s[n] * SC;
      const unsigned z = (lam > dc[i]) ? 1u : 0u;
      zwg[(size_t)t * 512] = (unsigned char)z;
      zprev = z;
    }
#pragma unroll
    for (int i = 0; i < 8; ++i) dc[i] = dnx[i];
  }
}

// ---------------- 5. vsz: scan z8 -> vt/zt floats + out = s@G^T + X@M^T ----------------
// Block per b. Per 64-step chunk: stage z8 chunk + X chunk -> LDS; scan (exact
// fp32 recurrence) writing vt/zt and bf16 s-tile; MFMA [64t x 128o] over
// K=512 (G) + K=128 (M); overwrite the consumed z8 chunk in-place with out.
__launch_bounds__(512)
__global__ void vsz_kernel(const float* __restrict__ X, const unsigned char* __restrict__ ws,
                           float* __restrict__ vt, float* __restrict__ zt,
                           float* __restrict__ op) {
  __shared__ unsigned zl[8192];              // 32KB z8 chunk
  __shared__ unsigned short sl[64 * 520];    // s bf16 [64 t][512 n], pad 8
  __shared__ unsigned short xl[64 * 136];    // X bf16 [64 t][128 i], pad 8
  const int b = blockIdx.x;
  const int tid = threadIdx.x;
  const int w = tid >> 6, l = tid & 63, lhi = l >> 4, llo = l & 15;
  const unsigned short* gpk = (const unsigned short*)(ws + OFF_GPK);
  const unsigned short* mpk = (const unsigned short*)(ws + OFF_MPK);
  const unsigned char* z8 = (const unsigned char*)op;

  float v = 0.0f;
  unsigned zprev = 0u;
  // t = 0 slots
  vt[((size_t)b * 513) * 512 + tid] = 0.0f;
  zt[((size_t)b * 513) * 512 + tid] = 0.0f;

  for (int c = 0; c < 8; ++c) {
    // --- stage z8 chunk + X chunk ---
    const uint4* src = (const uint4*)(z8 + (size_t)b * 262144 + (size_t)c * 32768);
#pragma unroll
    for (int i = 0; i < 4; ++i) ((uint4*)zl)[i * 512 + tid] = src[i * 512 + tid];
#pragma unroll
    for (int i = 0; i < 4; ++i) {
      const int idx = i * 512 + tid;            // 0..2047
      const int r = idx >> 5, c4 = (idx & 31) * 4;
      const float4 x4 = *(const float4*)(X + ((size_t)b * 512 + c * 64 + r) * 128 + c4);
      short4 h4;
      h4.x = (short)f2bf(x4.x); h4.y = (short)f2bf(x4.y);
      h4.z = (short)f2bf(x4.z); h4.w = (short)f2bf(x4.w);
      *(short4*)(xl + r * 136 + c4) = h4;
    }
    __syncthreads();
    // --- scan 64 steps (thread owns n = tid) ---
    const unsigned char* zb = (const unsigned char*)zl;
    float* vrow = vt + ((size_t)b * 513 + c * 64 + 1) * 512 + tid;
    float* zrow = zt + ((size_t)b * 513 + c * 64 + 1) * 512 + tid;
#pragma unroll 8
    for (int tl = 0; tl < 64; ++tl) {
      v = __builtin_fmaf(0.9f, v, zprev ? 0.1f : 0.0f);
      const unsigned z = zb[tl * 512 + tid];
      vrow[(size_t)tl * 512] = v;
      zrow[(size_t)tl * 512] = z ? 1.0f : 0.0f;
      sl[tl * 520 + tid] = f2bf(fast_tanh_pos(v));
      zprev = z;
    }
    __syncthreads();
    // --- MFMA: C[64 t][128 o]; wave w: m-tile = w>>1, o-tiles (w&1)*4 + 0..3 ---
    const int m = w >> 1, oh = (w & 1) * 4;
    f32x4 a0 = {0,0,0,0}, a1 = {0,0,0,0}, a2 = {0,0,0,0}, a3 = {0,0,0,0};
#pragma unroll
    for (int kt = 0; kt < 16; ++kt) {
      const short8x A = *(const short8x*)(sl + (m * 16 + llo) * 520 + kt * 32 + lhi * 8);
#define GT(TI, ACC) { \
      const short8x B = *(const short8x*)(gpk + ((size_t)((kt * 4 + lhi) * 128 + (oh + TI) * 16 + llo)) * 8); \
      ACC = __builtin_amdgcn_mfma_f32_16x16x32_bf16(A, B, ACC, 0, 0, 0); }
      GT(0, a0) GT(1, a1) GT(2, a2) GT(3, a3)
#undef GT
    }
#pragma unroll
    for (int kt = 0; kt < 4; ++kt) {
      const short8x A = *(const short8x*)(xl + (m * 16 + llo) * 136 + kt * 32 + lhi * 8);
#define MT(TI, ACC) { \
      const short8x B = *(const short8x*)(mpk + ((size_t)((kt * 4 + lhi) * 128 + (oh + TI) * 16 + llo)) * 8); \
      ACC = __builtin_amdgcn_mfma_f32_16x16x32_bf16(A, B, ACC, 0, 0, 0); }
      MT(0, a0) MT(1, a1) MT(2, a2) MT(3, a3)
#undef MT
    }
    // --- overwrite consumed z8 chunk with out floats ---
    float* obase = op + ((size_t)b * 512 + c * 64 + m * 16 + lhi * 4) * 128 + llo;
#pragma unroll
    for (int r = 0; r < 4; ++r) {
      float* orow = obase + (size_t)r * 128;
      orow[(oh + 0) * 16] = a0[r];
      orow[(oh + 1) * 16] = a1[r];
      orow[(oh + 2) * 16] = a2[r];
      orow[(oh + 3) * 16] = a3[r];
    }
    __syncthreads();   // protect zl/sl/xl before next chunk's staging
  }
}

extern "C" void kernel_launch(void* const* d_in, const int* in_sizes, int n_in,
                              void* d_out, int out_size, void* d_ws, size_t ws_size,
                              hipStream_t stream) {
  const float* X  = (const float*)d_in[0];   // inputs [128,512,128]
  const float* U  = (const float*)d_in[1];   // rand_u [128,512,512]
  const float* J  = (const float*)d_in[2];   // [512,512]
  const float* Bw = (const float*)d_in[3];   // [512,128]
  const float* W  = (const float*)d_in[4];   // [128,512]
  float* vt = (float*)d_out;
  float* zt = vt + (size_t)128 * 513 * 512;
  float* op = vt + (size_t)2 * 128 * 513 * 512;
  unsigned char* ws = (unsigned char*)d_ws;
  float* Dbuf = vt;                                   // D fp32 [bt][n] in vt region
  unsigned char* z8 = (unsigned char*)op;             // z bytes in out region

  jwm_kernel<<<128, 512, 0, stream>>>(J, Bw, W, ws);
  pack_kernel<<<136, 256, 0, stream>>>(J, Bw, ws);
  xpd_kernel<<<dim3(1024, 8), 256, 0, stream>>>(X, U, ws, Dbuf);
  recur_kernel<<<128, 512, 0, stream>>>(ws, Dbuf, z8);
  vsz_kernel<<<128, 512, 0, stream>>>(X, ws, vt, zt, op);
}